// Round 11
// baseline (897.258 us; speedup 1.0000x reference)
//
#include <hip/hip_runtime.h>
#include <math.h>

// DIAGNOSTIC ROUND 2: same phase ablation as R10, but with asymmetric grid
// amplification so BOTH phase times are recoverable:
//   caps_kernel<1> x4  grid : u_hat only        -> t1 = (dur_us - 16*t2 - 90)/4
//   caps_kernel<2> x16 grid : routing only      -> t2 = top5_table_dur / 16
//   caps_kernel<0> x1  grid : verified R7 full  -> writes d_out (LAST)
// R10 learned t1 + t2 = 76 us (additive) but top-5 flooding hid the split;
// 16*t2 (>=320us) and 4*t1 (<=220us) are disjoint so the table shows probe2
// unambiguously (signature: FETCH ~ 0), and dur_us gives t1 by subtraction.

#define IC 32
#define ID 16
#define NC 16
#define O  256            // NC*DC
#define BBPAD 20          // bb row stride (floats): 80 B, 16B-aligned rows
#define CPAD  36          // cc row stride (floats): 144 B, 16B-aligned rows

__device__ __forceinline__ float reduce16(float v) {
    v += __shfl_xor(v, 1);
    v += __shfl_xor(v, 2);
    v += __shfl_xor(v, 4);
    v += __shfl_xor(v, 8);
    return v;
}

__device__ __forceinline__ float squash16(float v) {
    float s2 = reduce16(v * v);
    return v * (s2 / ((1.0f + s2) * sqrtf(s2 + 1e-7f)));
}

template <int ACC>
__device__ __forceinline__ void b_update(const float (&r)[IC], float out, int d,
                                         float* __restrict__ bbcol)
{
    #pragma unroll
    for (int c = 0; c < 4; ++c) {
        float v[8];
        #pragma unroll
        for (int j = 0; j < 8; ++j) v[j] = out * r[8 * c + j];
        int idx = 8 * c;
        #pragma unroll
        for (int s = 0; s < 3; ++s) {            // items 8 -> 4 -> 2 -> 1
            const int mask = 1 << s;
            const int half = 4 >> s;             // 4, 2, 1
            const bool hi = (d & mask) != 0;
            if (hi) idx += half;
            #pragma unroll
            for (int j = 0; j < half; ++j) {
                float recv = __shfl_xor(hi ? v[j] : v[j + half], mask);
                v[j] = (hi ? v[j + half] : v[j]) + recv;
            }
        }
        v[0] += __shfl_xor(v[0], 8);             // final 16-lane sum (dup on d, d+8)
        if (d < 8) {                             // 8 lanes x 4 chunks cover i=0..31
            if (ACC) bbcol[idx * BBPAD] += v[0];
            else     bbcol[idx * BBPAD]  = v[0];
        }
    }
}

// MODE 0 = full (R7, real output) | 1 = u_hat only | 2 = routing only
template <int MODE>
__global__ __launch_bounds__(256, 4)
void caps_kernel(const float* __restrict__ inp,   // [B,N,IC,ID]
                 const float* __restrict__ W,     // [IC,ID,O]
                 float* __restrict__ outp)        // [B,N,NC,DC]
{
    const int t = threadIdx.x;
    const int pair0 = (blockIdx.x & 2047) * 2;   // amplified grids wrap

    __shared__ __align__(16) float bb[2][IC][BBPAD];  // logits, TRANSPOSED [i][k]
    __shared__ __align__(16) float cc[2][NC][CPAD];   // softmax coeffs [k][i]

    float r0[IC], r1[IC];

    if constexpr (MODE != 2) {
        // ---- real u_hat: rg[i] = sum_dd x_g[i][dd] * W[i][dd][t]
        const float* x0 = inp + (size_t)pair0 * (IC * ID);
        const float* x1 = x0 + IC * ID;
        #pragma unroll
        for (int i = 0; i < IC; ++i) {
            float a0 = 0.f, a1 = 0.f;
            #pragma unroll
            for (int dd = 0; dd < ID; ++dd) {
                float w = W[(i * ID + dd) * O + t];   // coalesced, L2-resident
                a0 = fmaf(w, x0[i * ID + dd], a0);    // x block-uniform -> s_load
                a1 = fmaf(w, x1[i * ID + dd], a1);
            }
            r0[i] = a0; r1[i] = a1;
        }
    } else {
        // ---- synthetic u_hat (2 VALU ops/elem, no memory)
        #pragma unroll
        for (int i = 0; i < IC; ++i) {
            r0[i] = (float)((t * 29 + i * 13) & 31) * 0.0625f - 1.0f;
            r1[i] = (float)((t * 17 + i * 7)  & 31) * 0.0625f - 1.0f;
        }
    }

    if constexpr (MODE == 1) {
        // keep u_hat alive without any store (guide rule #17)
        float s = 0.f;
        #pragma unroll
        for (int i = 0; i < IC; ++i) s = fmaf(r0[i], 1.0009765625f, s) + r1[i];
        asm volatile("" :: "v"(s));
        return;
    }

    const int k = t >> 4;
    const int d = t & 15;
    float* bbc0 = &bb[0][0][k];
    float* bbc1 = &bb[1][0][k];

    // ---- routing iter 0: b = 0 -> c = 1/16 uniform (softmax skipped)
    float o0 = 0.f, o1 = 0.f;
    #pragma unroll
    for (int i = 0; i < IC; ++i) { o0 += r0[i]; o1 += r1[i]; }
    o0 = squash16(o0 * 0.0625f);
    o1 = squash16(o1 * 0.0625f);
    b_update<0>(r0, o0, d, bbc0);
    b_update<0>(r1, o1, d, bbc1);
    __syncthreads();

    #pragma unroll
    for (int it = 1; it < 3; ++it) {
        // ---- softmax over NC; lanes 0-31: pair0, 32-63: pair1 (4x b128 reads)
        if (t < 64) {
            const int p = t >> 5, ii = t & 31;
            const float4* brow = (const float4*)&bb[p][ii][0];
            float4 b0 = brow[0], b1 = brow[1], b2 = brow[2], b3 = brow[3];
            float m = fmaxf(fmaxf(fmaxf(b0.x, b0.y), fmaxf(b0.z, b0.w)),
                            fmaxf(fmaxf(b1.x, b1.y), fmaxf(b1.z, b1.w)));
            m = fmaxf(m, fmaxf(fmaxf(fmaxf(b2.x, b2.y), fmaxf(b2.z, b2.w)),
                               fmaxf(fmaxf(b3.x, b3.y), fmaxf(b3.z, b3.w))));
            b0.x = __expf(b0.x - m); b0.y = __expf(b0.y - m);
            b0.z = __expf(b0.z - m); b0.w = __expf(b0.w - m);
            b1.x = __expf(b1.x - m); b1.y = __expf(b1.y - m);
            b1.z = __expf(b1.z - m); b1.w = __expf(b1.w - m);
            b2.x = __expf(b2.x - m); b2.y = __expf(b2.y - m);
            b2.z = __expf(b2.z - m); b2.w = __expf(b2.w - m);
            b3.x = __expf(b3.x - m); b3.y = __expf(b3.y - m);
            b3.z = __expf(b3.z - m); b3.w = __expf(b3.w - m);
            float s = ((b0.x + b0.y) + (b0.z + b0.w))
                    + ((b1.x + b1.y) + (b1.z + b1.w))
                    + ((b2.x + b2.y) + (b2.z + b2.w))
                    + ((b3.x + b3.y) + (b3.z + b3.w));
            float si = 1.0f / s;
            cc[p][ 0][ii] = b0.x * si; cc[p][ 1][ii] = b0.y * si;
            cc[p][ 2][ii] = b0.z * si; cc[p][ 3][ii] = b0.w * si;
            cc[p][ 4][ii] = b1.x * si; cc[p][ 5][ii] = b1.y * si;
            cc[p][ 6][ii] = b1.z * si; cc[p][ 7][ii] = b1.w * si;
            cc[p][ 8][ii] = b2.x * si; cc[p][ 9][ii] = b2.y * si;
            cc[p][10][ii] = b2.z * si; cc[p][11][ii] = b2.w * si;
            cc[p][12][ii] = b3.x * si; cc[p][13][ii] = b3.y * si;
            cc[p][14][ii] = b3.z * si; cc[p][15][ii] = b3.w * si;
        }
        __syncthreads();

        // ---- out[k][d] = sum_i c[k][i]*u_hat[k][i][d], c read as float4
        const float4* c0 = (const float4*)&cc[0][k][0];
        const float4* c1 = (const float4*)&cc[1][k][0];
        o0 = 0.f; o1 = 0.f;
        #pragma unroll
        for (int q = 0; q < IC / 4; ++q) {
            float4 v0 = c0[q], v1 = c1[q];
            o0 = fmaf(v0.x, r0[4*q+0], o0); o0 = fmaf(v0.y, r0[4*q+1], o0);
            o0 = fmaf(v0.z, r0[4*q+2], o0); o0 = fmaf(v0.w, r0[4*q+3], o0);
            o1 = fmaf(v1.x, r1[4*q+0], o1); o1 = fmaf(v1.y, r1[4*q+1], o1);
            o1 = fmaf(v1.z, r1[4*q+2], o1); o1 = fmaf(v1.w, r1[4*q+3], o1);
        }

        if (it < 2) {
            o0 = squash16(o0);
            o1 = squash16(o1);
            b_update<1>(r0, o0, d, bbc0);
            b_update<1>(r1, o1, d, bbc1);
            __syncthreads();
        }
    }

    if constexpr (MODE == 0) {
        outp[(size_t)pair0 * O + t]       = o0;   // coalesced
        outp[((size_t)pair0 + 1) * O + t] = o1;
    } else {
        asm volatile("" :: "v"(o0), "v"(o1));     // routing-probe: no store
    }
}

extern "C" void kernel_launch(void* const* d_in, const int* in_sizes, int n_in,
                              void* d_out, int out_size, void* d_ws, size_t ws_size,
                              hipStream_t stream) {
    const float* inp = (const float*)d_in[0];   // [32,128,32,16] fp32
    const float* W   = (const float*)d_in[1];   // [32,16,256]   fp32
    float* outp      = (float*)d_out;           // [32,128,16,16] fp32

    dim3 block(256);
    // probes first (no global stores), amplified grids; real kernel LAST.
    hipLaunchKernelGGL((caps_kernel<1>), dim3(2048 * 4),  block, 0, stream, inp, W, outp);
    hipLaunchKernelGGL((caps_kernel<2>), dim3(2048 * 16), block, 0, stream, inp, W, outp);
    hipLaunchKernelGGL((caps_kernel<0>), dim3(2048),      block, 0, stream, inp, W, outp);
}

// Round 12
// 80.420 us; speedup vs baseline: 11.1571x; 11.1571x over previous
//
#include <hip/hip_runtime.h>
#include <math.h>

// CapsNet dynamic routing, fused, 2 pairs/block — R7 skeleton (verified).
// R11 diagnosis: u_hat ~8.5us, routing ~48us (latency-bound serial chains;
// occupancy reg-capped at 4 waves/SIMD by r-in-AGPR). R12 shortens the two
// dominant serial chains:
//  - softmax spread 64 -> 256 threads (4-lane group per (pair,i), 4 k's
//    each: 1x b128 read, shfl-tree max/sum, 4 exp) — kills the 192-thread
//    barrier bubble and cuts the serial body ~4x.
//  - einsum + iter0-sum: 4 independent accumulator chains (was 32-deep).
// b_update / u_hat / stores byte-identical to R7.

#define IC 32
#define ID 16
#define NC 16
#define O  256            // NC*DC
#define BBPAD 20          // bb row stride (floats): 80 B, 16B-aligned rows
#define CPAD  36          // cc row stride (floats): 144 B, 16B-aligned rows

__device__ __forceinline__ float reduce16(float v) {
    v += __shfl_xor(v, 1);
    v += __shfl_xor(v, 2);
    v += __shfl_xor(v, 4);
    v += __shfl_xor(v, 8);
    return v;
}

__device__ __forceinline__ float squash16(float v) {
    float s2 = reduce16(v * v);
    return v * (s2 / ((1.0f + s2) * sqrtf(s2 + 1e-7f)));
}

template <int ACC>
__device__ __forceinline__ void b_update(const float (&r)[IC], float out, int d,
                                         float* __restrict__ bbcol)
{
    #pragma unroll
    for (int c = 0; c < 4; ++c) {
        float v[8];
        #pragma unroll
        for (int j = 0; j < 8; ++j) v[j] = out * r[8 * c + j];
        int idx = 8 * c;
        #pragma unroll
        for (int s = 0; s < 3; ++s) {            // items 8 -> 4 -> 2 -> 1
            const int mask = 1 << s;
            const int half = 4 >> s;             // 4, 2, 1
            const bool hi = (d & mask) != 0;
            if (hi) idx += half;
            #pragma unroll
            for (int j = 0; j < half; ++j) {
                float recv = __shfl_xor(hi ? v[j] : v[j + half], mask);
                v[j] = (hi ? v[j + half] : v[j]) + recv;
            }
        }
        v[0] += __shfl_xor(v[0], 8);             // final 16-lane sum (dup on d, d+8)
        if (d < 8) {                             // 8 lanes x 4 chunks cover i=0..31
            if (ACC) bbcol[idx * BBPAD] += v[0];
            else     bbcol[idx * BBPAD]  = v[0];
        }
    }
}

__global__ __launch_bounds__(256, 4)
void capsule_routing_kernel(const float* __restrict__ inp,   // [B,N,IC,ID]
                            const float* __restrict__ W,     // [IC,ID,O]
                            float* __restrict__ outp)        // [B,N,NC,DC]
{
    const int t = threadIdx.x;
    const int pair0 = blockIdx.x * 2;

    __shared__ __align__(16) float bb[2][IC][BBPAD];  // logits, TRANSPOSED [i][k]
    __shared__ __align__(16) float cc[2][NC][CPAD];   // softmax coeffs [k][i]

    // ---- u_hat: rg[i] = sum_dd x_g[i][dd] * W[i][dd][t]
    float r0[IC], r1[IC];
    const float* x0 = inp + (size_t)pair0 * (IC * ID);
    const float* x1 = x0 + IC * ID;

    #pragma unroll
    for (int i = 0; i < IC; ++i) {
        float a0 = 0.f, a1 = 0.f;
        #pragma unroll
        for (int dd = 0; dd < ID; ++dd) {
            float w = W[(i * ID + dd) * O + t];   // coalesced, L2-resident
            a0 = fmaf(w, x0[i * ID + dd], a0);    // x block-uniform -> s_load
            a1 = fmaf(w, x1[i * ID + dd], a1);
        }
        r0[i] = a0; r1[i] = a1;
    }

    const int k = t >> 4;
    const int d = t & 15;
    float* bbc0 = &bb[0][0][k];
    float* bbc1 = &bb[1][0][k];

    // ---- routing iter 0: b = 0 -> c = 1/16 uniform (softmax skipped)
    // 4 independent accumulation chains per pair
    float s0a = 0.f, s0b = 0.f, s0c = 0.f, s0d = 0.f;
    float s1a = 0.f, s1b = 0.f, s1c = 0.f, s1d = 0.f;
    #pragma unroll
    for (int i = 0; i < IC; i += 4) {
        s0a += r0[i];     s0b += r0[i + 1];
        s0c += r0[i + 2]; s0d += r0[i + 3];
        s1a += r1[i];     s1b += r1[i + 1];
        s1c += r1[i + 2]; s1d += r1[i + 3];
    }
    float o0 = (s0a + s0b) + (s0c + s0d);
    float o1 = (s1a + s1b) + (s1c + s1d);
    o0 = squash16(o0 * 0.0625f);
    o1 = squash16(o1 * 0.0625f);
    b_update<0>(r0, o0, d, bbc0);
    b_update<0>(r1, o1, d, bbc1);
    __syncthreads();

    #pragma unroll
    for (int it = 1; it < 3; ++it) {
        // ---- softmax over NC, ALL 256 threads active:
        // p = t>>7 (pair), ii = (t>>2)&31 (input capsule), j = t&3 (k-quad).
        // 4-lane groups (consecutive j) reduce max/sum via shfl_xor 1,2.
        {
            const int p = t >> 7, ii = (t >> 2) & 31, j = t & 3;
            const float4* brow = (const float4*)&bb[p][ii][0];
            float4 b0 = brow[j];
            float m = fmaxf(fmaxf(b0.x, b0.y), fmaxf(b0.z, b0.w));
            m = fmaxf(m, __shfl_xor(m, 1));
            m = fmaxf(m, __shfl_xor(m, 2));
            b0.x = __expf(b0.x - m); b0.y = __expf(b0.y - m);
            b0.z = __expf(b0.z - m); b0.w = __expf(b0.w - m);
            float s = (b0.x + b0.y) + (b0.z + b0.w);
            s += __shfl_xor(s, 1);
            s += __shfl_xor(s, 2);
            float si = 1.0f / s;
            const int k4 = j * 4;
            cc[p][k4 + 0][ii] = b0.x * si;
            cc[p][k4 + 1][ii] = b0.y * si;
            cc[p][k4 + 2][ii] = b0.z * si;
            cc[p][k4 + 3][ii] = b0.w * si;
        }
        __syncthreads();

        // ---- out[k][d] = sum_i c[k][i]*u_hat[k][i][d]; float4 c reads,
        // 4 independent fma chains per pair (was one 32-deep chain).
        const float4* c0 = (const float4*)&cc[0][k][0];
        const float4* c1 = (const float4*)&cc[1][k][0];
        float a0 = 0.f, b0_ = 0.f, e0 = 0.f, f0 = 0.f;
        float a1 = 0.f, b1_ = 0.f, e1 = 0.f, f1 = 0.f;
        #pragma unroll
        for (int q = 0; q < IC / 4; ++q) {
            float4 v0 = c0[q], v1 = c1[q];
            a0  = fmaf(v0.x, r0[4*q+0], a0);
            b0_ = fmaf(v0.y, r0[4*q+1], b0_);
            e0  = fmaf(v0.z, r0[4*q+2], e0);
            f0  = fmaf(v0.w, r0[4*q+3], f0);
            a1  = fmaf(v1.x, r1[4*q+0], a1);
            b1_ = fmaf(v1.y, r1[4*q+1], b1_);
            e1  = fmaf(v1.z, r1[4*q+2], e1);
            f1  = fmaf(v1.w, r1[4*q+3], f1);
        }
        o0 = (a0 + b0_) + (e0 + f0);
        o1 = (a1 + b1_) + (e1 + f1);

        if (it < 2) {
            o0 = squash16(o0);
            o1 = squash16(o1);
            b_update<1>(r0, o0, d, bbc0);
            b_update<1>(r1, o1, d, bbc1);
            __syncthreads();
        }
    }

    // ---- final iter: no squash; coalesced stores
    outp[(size_t)pair0 * O + t]       = o0;
    outp[((size_t)pair0 + 1) * O + t] = o1;
}

extern "C" void kernel_launch(void* const* d_in, const int* in_sizes, int n_in,
                              void* d_out, int out_size, void* d_ws, size_t ws_size,
                              hipStream_t stream) {
    const float* inp = (const float*)d_in[0];   // [32,128,32,16] fp32
    const float* W   = (const float*)d_in[1];   // [32,16,256]   fp32
    float* outp      = (float*)d_out;           // [32,128,16,16] fp32

    const int npairs = 32 * 128;                // B*N = 4096
    dim3 grid(npairs / 2), block(256);
    hipLaunchKernelGGL(capsule_routing_kernel, grid, block, 0, stream,
                       inp, W, outp);
}